// Round 20
// baseline (144.720 us; speedup 1.0000x reference)
//
#include <hip/hip_runtime.h>
#include <hip/hip_bf16.h>

// RandomProjectionQuantizer — R20: full-occupancy screen + paired project.
//  x:(16,2048,320) f32, mask:(16,2048) i32 (exactly 16384 ones),
//  W:(16,320) f32, codebook:(8192,16) f32 -> scalar int32 label
//
//  init    : counters + key.
//  project : 256 blocks x 256, block = 128 rows; pos[] rank table from
//            ballots; pair-path = 2 rows/thread sharing W LDS-reads
//            (per-row FMA chain preserved -> bit-identical to proj_lds);
//            fused codes job (-2c hi/lo + c2 + cnrm) + rowmin init.
//  phase1  : 2048 blocks x 256 (8192 waves = full occupancy); wave = 32 rows
//            x 512 codes; 2-MFMA fused screen (R19-proven formula); LDS merge
//            + global atomicMin (R7-proven).
//  gatecp  : 1 block x 1024 — gate + cproj (R17-proven structure, nc tiny).
//  rescore : 512 x 256 (R19-verbatim).

#define NMASK   16384
#define NROWS   32768
#define D       320
#define CDIM    16
#define NCODES  8192
#define EPS_C   2e-4f        // >> 2-level screen error coefficient (~1e-5)
#define EPS_ABS 0.02f

typedef __attribute__((ext_vector_type(8))) short short8;
typedef __attribute__((ext_vector_type(4))) float f32x4;

__device__ inline unsigned int encf(float f) {
  unsigned int u = __float_as_uint(f);
  return (u & 0x80000000u) ? ~u : (u | 0x80000000u);
}
__device__ inline float decf(unsigned int u) {
  unsigned int b = (u & 0x80000000u) ? (u & 0x7fffffffu) : ~u;
  return __uint_as_float(b);
}
__device__ inline unsigned short f2bf(float f) {   // RNE f32->bf16
  unsigned int u = __float_as_uint(f);
  unsigned int r = u + 0x7fffu + ((u >> 16) & 1u);
  return (unsigned short)(r >> 16);
}
__device__ inline float bf2f(unsigned short h) {
  return __uint_as_float(((unsigned int)h) << 16);
}

// LDS-W projection body (R12/R14-proven). Per-row chain: for j, for c, 4 FMAs.
__device__ inline void proj_lds(const float* __restrict__ x,
                                const float* __restrict__ Wl,
                                int row, int ch, float pd[16]) {
  const float* xr = x + (size_t)row * D + ch * 4;
  float4 xv[10];
#pragma unroll
  for (int j = 0; j < 10; ++j) xv[j] = *(const float4*)(xr + j * 32);
#pragma unroll
  for (int c = 0; c < 16; ++c) pd[c] = 0.f;
#pragma unroll
  for (int j = 0; j < 10; ++j) {
#pragma unroll
    for (int c = 0; c < 16; ++c) {
      const float4 wv = *(const float4*)&Wl[c * D + j * 32 + ch * 4];
      float acc = fmaf(xv[j].x, wv.x, pd[c]);
      acc = fmaf(xv[j].y, wv.y, acc);
      acc = fmaf(xv[j].z, wv.z, acc);
      pd[c] = fmaf(xv[j].w, wv.w, acc);
    }
  }
#pragma unroll
  for (int c = 0; c < 16; ++c) {
    pd[c] += __shfl_xor(pd[c], 1);
    pd[c] += __shfl_xor(pd[c], 2);
    pd[c] += __shfl_xor(pd[c], 4);
  }
}

// store projected row: t2, origrow, [t_hi|t_lo] bf16 pairs. ch==0 lanes only.
__device__ inline void store_t(const float pd[16], int slot, int row,
                               float* __restrict__ t2arr,
                               int* __restrict__ origrow,
                               unsigned short* __restrict__ tbf32) {
  float t2 = 0.f;
#pragma unroll
  for (int c = 0; c < 16; ++c) t2 = fmaf(pd[c], pd[c], t2);
  t2arr[slot] = t2;
  origrow[slot] = row;
  unsigned short th[16], tl[16];
#pragma unroll
  for (int c = 0; c < 16; ++c) {
    unsigned short hi = f2bf(pd[c]);
    th[c] = hi;
    tl[c] = f2bf(pd[c] - bf2f(hi));
  }
  uint4 pk0, pk1, pk2, pk3;
  pk0.x = (unsigned int)th[0]  | ((unsigned int)th[1]  << 16);
  pk0.y = (unsigned int)th[2]  | ((unsigned int)th[3]  << 16);
  pk0.z = (unsigned int)th[4]  | ((unsigned int)th[5]  << 16);
  pk0.w = (unsigned int)th[6]  | ((unsigned int)th[7]  << 16);
  pk1.x = (unsigned int)th[8]  | ((unsigned int)th[9]  << 16);
  pk1.y = (unsigned int)th[10] | ((unsigned int)th[11] << 16);
  pk1.z = (unsigned int)th[12] | ((unsigned int)th[13] << 16);
  pk1.w = (unsigned int)th[14] | ((unsigned int)th[15] << 16);
  pk2.x = (unsigned int)tl[0]  | ((unsigned int)tl[1]  << 16);
  pk2.y = (unsigned int)tl[2]  | ((unsigned int)tl[3]  << 16);
  pk2.z = (unsigned int)tl[4]  | ((unsigned int)tl[5]  << 16);
  pk2.w = (unsigned int)tl[6]  | ((unsigned int)tl[7]  << 16);
  pk3.x = (unsigned int)tl[8]  | ((unsigned int)tl[9]  << 16);
  pk3.y = (unsigned int)tl[10] | ((unsigned int)tl[11] << 16);
  pk3.z = (unsigned int)tl[12] | ((unsigned int)tl[13] << 16);
  pk3.w = (unsigned int)tl[14] | ((unsigned int)tl[15] << 16);
  uint4* dst = (uint4*)(tbf32 + (long)slot * 32);
  dst[0] = pk0; dst[1] = pk1; dst[2] = pk2; dst[3] = pk3;
}

// ---------------- Kernel 0: init (1 block x 64) ------------------------------
__global__ void init_kernel(unsigned int* __restrict__ ctrs,
                            unsigned long long* __restrict__ key) {
  if (threadIdx.x < 4) ctrs[threadIdx.x] = 0u;      // slotctr, resctr (+spare)
  if (threadIdx.x == 4) key[0] = 0xFFFFFFFFFFFFFFFFull;
}

// ---------------- Kernel 1: project (256 blocks x 256) -----------------------
__global__ __launch_bounds__(256) void project_kernel(
    const float* __restrict__ x, const int* __restrict__ mask,
    const float* __restrict__ W, const float* __restrict__ cbk,
    float* __restrict__ c2, unsigned int* __restrict__ cnrm,
    unsigned short* __restrict__ cbf32, unsigned short* __restrict__ tbf32,
    float* __restrict__ t2arr, int* __restrict__ origrow,
    unsigned int* __restrict__ rowmin_u, unsigned int* __restrict__ slotctr) {
  __shared__ float Wl[CDIM * D];                    // 20 KiB
  __shared__ unsigned long long mbs[2];
  __shared__ int pos[128];
  __shared__ unsigned int base_s;
  int tid = threadIdx.x, bid = (int)blockIdx.x;
  int rbase = bid * 128;
  for (int i = tid; i < (CDIM * D) / 4; i += 256)
    ((float4*)Wl)[i] = ((const float4*)W)[i];
  if (tid < 128) {                                  // waves 0,1: ballots
    int m = mask[rbase + tid];
    unsigned long long bal = __ballot(m != 0);
    if ((tid & 63) == 0) mbs[tid >> 6] = bal;
  }
  if (tid < 64) rowmin_u[bid * 64 + tid] = 0xFFFFFFFFu;   // 256*64 = 16384
  __syncthreads();

  if (tid < 32) {                                   // codes job: 256*32 = 8192
    int k = bid * 32 + tid;
    const float4* p = (const float4*)(cbk + (long)k * CDIM);
    float s = 0.f; unsigned short chv[16], clv[16];
#pragma unroll
    for (int q = 0; q < 4; ++q) {
      float4 v = p[q];
      s = fmaf(v.x, v.x, s); s = fmaf(v.y, v.y, s);
      s = fmaf(v.z, v.z, s); s = fmaf(v.w, v.w, s);
      float m2[4] = {-2.0f * v.x, -2.0f * v.y, -2.0f * v.z, -2.0f * v.w};
#pragma unroll
      for (int e = 0; e < 4; ++e) {
        unsigned short hi = f2bf(m2[e]);
        chv[q*4+e] = hi;
        clv[q*4+e] = f2bf(m2[e] - bf2f(hi));
      }
    }
    c2[k] = s;
    unsigned short g1 = f2bf(s), g2 = f2bf(s - bf2f(g1));
    cnrm[k] = (unsigned int)g1 | ((unsigned int)g2 << 16);
    uint4 pk0, pk1, pk2, pk3;
    pk0.x = (unsigned int)chv[0]  | ((unsigned int)chv[1]  << 16);
    pk0.y = (unsigned int)chv[2]  | ((unsigned int)chv[3]  << 16);
    pk0.z = (unsigned int)chv[4]  | ((unsigned int)chv[5]  << 16);
    pk0.w = (unsigned int)chv[6]  | ((unsigned int)chv[7]  << 16);
    pk1.x = (unsigned int)chv[8]  | ((unsigned int)chv[9]  << 16);
    pk1.y = (unsigned int)chv[10] | ((unsigned int)chv[11] << 16);
    pk1.z = (unsigned int)chv[12] | ((unsigned int)chv[13] << 16);
    pk1.w = (unsigned int)chv[14] | ((unsigned int)chv[15] << 16);
    pk2.x = (unsigned int)clv[0]  | ((unsigned int)clv[1]  << 16);
    pk2.y = (unsigned int)clv[2]  | ((unsigned int)clv[3]  << 16);
    pk2.z = (unsigned int)clv[4]  | ((unsigned int)clv[5]  << 16);
    pk2.w = (unsigned int)clv[6]  | ((unsigned int)clv[7]  << 16);
    pk3.x = (unsigned int)clv[8]  | ((unsigned int)clv[9]  << 16);
    pk3.y = (unsigned int)clv[10] | ((unsigned int)clv[11] << 16);
    pk3.z = (unsigned int)clv[12] | ((unsigned int)clv[13] << 16);
    pk3.w = (unsigned int)clv[14] | ((unsigned int)clv[15] << 16);
    uint4* dst = (uint4*)(cbf32 + (long)k * 32);
    dst[0] = pk0; dst[1] = pk1; dst[2] = pk2; dst[3] = pk3;
  }

  unsigned long long B0 = mbs[0], B1 = mbs[1];
  int cnt0 = __popcll(B0);
  int cnt  = cnt0 + __popcll(B1);
  if (tid < 64 && ((B0 >> tid) & 1ull))
    pos[__popcll(B0 & ((1ull << tid) - 1ull))] = tid;
  if (tid >= 64 && tid < 128 && ((B1 >> (tid - 64)) & 1ull))
    pos[cnt0 + __popcll(B1 & ((1ull << (tid - 64)) - 1ull))] = tid;  // 64+lane
  if (tid == 0) base_s = cnt ? atomicAdd(slotctr, (unsigned int)cnt) : 0u;
  __syncthreads();
  unsigned int base = base_s;

  int r = tid >> 3, ch = tid & 7;
  int idx0 = r, idx1 = r + 32;
  if (idx1 < cnt) {                                 // pair path (dominant)
    int row0 = rbase + pos[idx0], row1 = rbase + pos[idx1];
    const float* xr0 = x + (size_t)row0 * D + ch * 4;
    const float* xr1 = x + (size_t)row1 * D + ch * 4;
    float4 xv0[10], xv1[10];
#pragma unroll
    for (int j = 0; j < 10; ++j) { xv0[j] = *(const float4*)(xr0 + j * 32);
                                   xv1[j] = *(const float4*)(xr1 + j * 32); }
    float pd0[16], pd1[16];
#pragma unroll
    for (int c = 0; c < 16; ++c) { pd0[c] = 0.f; pd1[c] = 0.f; }
#pragma unroll
    for (int j = 0; j < 10; ++j) {
#pragma unroll
      for (int c = 0; c < 16; ++c) {                // shared W read, 2 rows
        const float4 wv = *(const float4*)&Wl[c * D + j * 32 + ch * 4];
        float a0 = fmaf(xv0[j].x, wv.x, pd0[c]);
        a0 = fmaf(xv0[j].y, wv.y, a0);
        a0 = fmaf(xv0[j].z, wv.z, a0);
        pd0[c] = fmaf(xv0[j].w, wv.w, a0);
        float a1 = fmaf(xv1[j].x, wv.x, pd1[c]);
        a1 = fmaf(xv1[j].y, wv.y, a1);
        a1 = fmaf(xv1[j].z, wv.z, a1);
        pd1[c] = fmaf(xv1[j].w, wv.w, a1);
      }
    }
#pragma unroll
    for (int c = 0; c < 16; ++c) {
      pd0[c] += __shfl_xor(pd0[c], 1);
      pd0[c] += __shfl_xor(pd0[c], 2);
      pd0[c] += __shfl_xor(pd0[c], 4);
    }
#pragma unroll
    for (int c = 0; c < 16; ++c) {
      pd1[c] += __shfl_xor(pd1[c], 1);
      pd1[c] += __shfl_xor(pd1[c], 2);
      pd1[c] += __shfl_xor(pd1[c], 4);
    }
    if (ch == 0) {
      store_t(pd0, (int)base + idx0, row0, t2arr, origrow, tbf32);
      store_t(pd1, (int)base + idx1, row1, t2arr, origrow, tbf32);
    }
  } else if (idx0 < cnt) {                          // single tail
    int row = rbase + pos[idx0];
    float pd[16];
    proj_lds(x, Wl, row, ch, pd);
    if (ch == 0) store_t(pd, (int)base + idx0, row, t2arr, origrow, tbf32);
  }
  // overflow ranks (cnt > 64): rare, handled by singles
  for (int idx = r + 64; idx < cnt; idx += 32) {
    int row = rbase + pos[idx];
    float pd[16];
    proj_lds(x, Wl, row, ch, pd);
    if (ch == 0) store_t(pd, (int)base + idx, row, t2arr, origrow, tbf32);
  }
}

// ---------------- Kernel 2: 2-MFMA screening (2048 blocks x 256) -------------
// strip = bid>>2 (32 slots); wave w covers seg (bid&3)*4+w (512 codes, 32 it).
// 8192 waves -> full occupancy. LDS merge + global atomicMin (R7-proven).
__global__ __launch_bounds__(256) void phase1_kernel(
    const unsigned short* __restrict__ tbf32,
    const unsigned short* __restrict__ cbf32,
    const unsigned int* __restrict__ cnrm,
    const float* __restrict__ t2arr,
    unsigned int* __restrict__ rowmin_u) {
  __shared__ unsigned int rml[4 * 33];
  int tid = threadIdx.x;
  int w = tid >> 6, l = tid & 63, lr = l & 15, g = l >> 4;
  int strip = (int)blockIdx.x >> 2;
  int seg   = ((int)blockIdx.x & 3) * 4 + w;
  int row0 = strip * 32;

  for (int i = tid; i < 4 * 33; i += 256) rml[i] = 0xFFFFFFFFu;

  const f32x4 zero = {0.f, 0.f, 0.f, 0.f};
  short8 calA = {0,0,0,0,0,0,0,0}, calB = {0,0,0,0,0,0,0,0};
  if (g == 0) {
    calA[0] = (short)f2bf((float)(lr + 1));
    calB[0] = (short)0x3F80;                        // bf16 1.0
  }
  f32x4 cal = __builtin_amdgcn_mfma_f32_16x16x32_bf16(calA, calB, zero, 0, 0, 0);
  int rid[4];
#pragma unroll
  for (int j = 0; j < 4; ++j) {
    int v = (int)(cal[j] + 0.5f) - 1;
    rid[j] = v < 0 ? 0 : (v > 15 ? 15 : v);
  }

  short8 a1[2], a2[2];
  f32x4 rmin[2];
#pragma unroll
  for (int rg = 0; rg < 2; ++rg) {
    int row = row0 + rg * 16 + lr;
    a1[rg] = *(const short8*)(tbf32 + (long)row * 32 + g * 8);
    short8 t = {0,0,0,0,0,0,0,0};
    if (g < 2) {
      t = a1[rg];                                   // t_hi chunks
    } else if (g == 2) {                            // [1,1,h1,h2] at k=16..19
      float t2v = t2arr[row];
      unsigned short h1 = f2bf(t2v), h2 = f2bf(t2v - bf2f(h1));
      t[0] = (short)0x3F80; t[1] = (short)0x3F80;
      t[2] = (short)h1;     t[3] = (short)h2;
    }
    a2[rg] = t;
    rmin[rg] = (f32x4){3.4e38f, 3.4e38f, 3.4e38f, 3.4e38f};
  }

  int code0 = seg * 512;
#pragma unroll 2
  for (int t = 0; t < 32; ++t) {
    int code = code0 + t * 16 + lr;
    const unsigned short* cb = cbf32 + (long)code * 32;
    short8 bh = *(const short8*)(cb + (g & 1) * 8); // [c_hi,c_hi] dup
    short8 b2 = {0,0,0,0,0,0,0,0};
    if (g < 2) {
      b2 = *(const short8*)(cb + 16 + g * 8);       // c_lo at k=0..15
    } else if (g == 2) {                            // [g1,g2,1,1] at k=16..19
      unsigned int cn = cnrm[code];
      b2[0] = (short)(cn & 0xFFFFu);
      b2[1] = (short)(cn >> 16);
      b2[2] = (short)0x3F80; b2[3] = (short)0x3F80;
    }
#pragma unroll
    for (int rg = 0; rg < 2; ++rg) {
      f32x4 d = __builtin_amdgcn_mfma_f32_16x16x32_bf16(a1[rg], bh, zero, 0, 0, 0);
      d = __builtin_amdgcn_mfma_f32_16x16x32_bf16(a2[rg], b2, d, 0, 0, 0);
#pragma unroll
      for (int j = 0; j < 4; ++j) rmin[rg][j] = fminf(rmin[rg][j], d[j]);
    }
  }
  __syncthreads();                                  // rml init complete
  unsigned int* myw = &rml[w * 33];
#pragma unroll
  for (int rg = 0; rg < 2; ++rg)
#pragma unroll
    for (int j = 0; j < 4; ++j)
      atomicMin(&myw[rg * 16 + rid[j]], encf(rmin[rg][j]));
  __syncthreads();
  if (tid < 32) {                                   // merge 4 waves -> global
    unsigned int mn = 0xFFFFFFFFu;
#pragma unroll
    for (int ww = 0; ww < 4; ++ww) mn = min(mn, rml[ww * 33 + tid]);
    atomicMin(&rowmin_u[row0 + tid], mn);
  }
}

// ---------------- Kernel 3: gatecp — gate + cproj (1 x 1024, R17-proven) -----
__global__ __launch_bounds__(1024) void gatecp_kernel(
    const float* __restrict__ x, const float* __restrict__ W,
    const float* __restrict__ c2, const float* __restrict__ t2arr,
    const int* __restrict__ origrow, const unsigned int* __restrict__ rowmin_u,
    unsigned int* __restrict__ candcount, int* __restrict__ candlist,
    float* __restrict__ tgtm) {
  __shared__ float Wl[CDIM * D];                    // 20 KiB
  __shared__ float red_f[1024];
  __shared__ unsigned int cnt_s;
  int tid = threadIdx.x;

  for (int i = tid; i < (CDIM * D) / 4; i += 1024)
    ((float4*)Wl)[i] = ((const float4*)W)[i];
  float cm = 0.f;                                   // c2max
  for (int i = tid; i < NCODES; i += 1024) cm = fmaxf(cm, c2[i]);
  red_f[tid] = cm;
  if (tid == 0) cnt_s = 0u;
  __syncthreads();
  for (int s = 512; s > 0; s >>= 1) {
    if (tid < s) red_f[tid] = fmaxf(red_f[tid], red_f[tid + s]);
    __syncthreads();
  }
  float c2m = red_f[0];
  __syncthreads();
  float Tl = 3.4e38f;                               // T = min(a + eps)
  for (int i = tid; i < NMASK; i += 1024) {
    float a = decf(rowmin_u[i]);
    float e = fmaf(EPS_C, sqrtf(t2arr[i] * c2m), EPS_ABS);
    Tl = fminf(Tl, a + e);                          // NaN -> ignored
  }
  red_f[tid] = Tl;
  __syncthreads();
  for (int s = 512; s > 0; s >>= 1) {
    if (tid < s) red_f[tid] = fminf(red_f[tid], red_f[tid + s]);
    __syncthreads();
  }
  float T = red_f[0];
  for (int i = tid; i < NMASK; i += 1024) {         // candidates
    float a = decf(rowmin_u[i]);
    float e = fmaf(EPS_C, sqrtf(t2arr[i] * c2m), EPS_ABS);
    if (!(a - e > T)) {                             // NaN-safe: NaN -> candidate
      unsigned int pos = atomicAdd(&cnt_s, 1u);
      candlist[pos] = i;
    }
  }
  __syncthreads();
  int nc = (int)cnt_s;
  if (tid == 0) candcount[0] = cnt_s;               // plain store
  int grp = tid >> 3, ch = tid & 7;                 // cproj: nc tiny post-R18
  for (int idx = grp; idx < nc; idx += 128) {
    int row = origrow[candlist[idx]];
    float pd[16];
    proj_lds(x, Wl, row, ch, pd);                   // bit-identical chain
    if (ch == 0) {
      float* op = tgtm + (long)idx * 16;
#pragma unroll
      for (int c = 0; c < 16; ++c) op[c] = -2.0f * pd[c];
    }
  }
}

// ---------------- Kernel 4: rescore + rank emit (512 x 256, R19-verbatim) ----
__global__ __launch_bounds__(256) void rescore_kernel(
    const float* __restrict__ cbk, const float* __restrict__ c2,
    const float* __restrict__ tgtm, const float* __restrict__ t2arr,
    const int* __restrict__ origrow, const int* __restrict__ mask,
    const unsigned int* __restrict__ candcount, const int* __restrict__ candlist,
    unsigned long long* __restrict__ key, unsigned int* __restrict__ resctr,
    int* __restrict__ out) {
  __shared__ unsigned long long red[256];
  __shared__ int lastf;
  __shared__ unsigned int vlow_s;
  int tid = threadIdx.x, bid = (int)blockIdx.x;
  int nwork = (int)candcount[0] * 8;                // 8 octants x 1024 codes
  for (int wk = bid; wk < nwork; wk += (int)gridDim.x) {
    int ci = wk >> 3, oct = wk & 7;
    int r = candlist[ci];                           // slot, uniform per block
    float t2 = t2arr[r];
    int row = origrow[r];
    float tm[16];
    const float4* tp = (const float4*)(tgtm + (long)ci * 16);
#pragma unroll
    for (int q = 0; q < 4; ++q) {                   // uniform -> scalar loads
      float4 v = tp[q];
      tm[q*4+0] = v.x; tm[q*4+1] = v.y; tm[q*4+2] = v.z; tm[q*4+3] = v.w;
    }
    float minv = 3.4e38f; int mink = 0;
#pragma unroll 2
    for (int k = 0; k < 4; ++k) {                   // 4 codes/thread
      int code = oct * 1024 + k * 256 + tid;
      const float4* cp = (const float4*)(cbk + (long)code * CDIM);
      float4 c0 = cp[0], c1 = cp[1], c2v4 = cp[2], c3 = cp[3];
      float acc = fmaf(tm[0],  c0.x, c2[code]);
      acc = fmaf(tm[1],  c0.y, acc);   acc = fmaf(tm[2],  c0.z, acc);
      acc = fmaf(tm[3],  c0.w, acc);   acc = fmaf(tm[4],  c1.x, acc);
      acc = fmaf(tm[5],  c1.y, acc);   acc = fmaf(tm[6],  c1.z, acc);
      acc = fmaf(tm[7],  c1.w, acc);   acc = fmaf(tm[8],  c2v4.x, acc);
      acc = fmaf(tm[9],  c2v4.y, acc); acc = fmaf(tm[10], c2v4.z, acc);
      acc = fmaf(tm[11], c2v4.w, acc); acc = fmaf(tm[12], c3.x, acc);
      acc = fmaf(tm[13], c3.y, acc);   acc = fmaf(tm[14], c3.z, acc);
      acc = fmaf(tm[15], c3.w, acc);
      if (acc < minv) { minv = acc; mink = code; }
    }
    // tie-break on row*8192+code == lexicographic (row, code) == rank order
    red[tid] = ((unsigned long long)encf(t2 + minv) << 32)
        | (unsigned long long)((unsigned int)row * (unsigned int)NCODES + (unsigned int)mink);
    __syncthreads();
    for (int s = 128; s > 0; s >>= 1) {
      if (tid < s) { if (red[tid + s] < red[tid]) red[tid] = red[tid + s]; }
      __syncthreads();
    }
    if (tid == 0) atomicMin(key, red[0]);
    __syncthreads();                                // LDS reuse across wk
  }
  if (tid == 0) {
    __threadfence();
    lastf = (atomicAdd(resctr, 1u) == (unsigned int)gridDim.x - 1u) ? 1 : 0;
  }
  __syncthreads();
  if (lastf) {                                      // last block: rank + emit
    if (tid == 0)
      vlow_s = (unsigned int)(atomicMin(key, 0xFFFFFFFFFFFFFFFFull) & 0xFFFFFFFFull);
    __syncthreads();
    unsigned int vlow = vlow_s;
    int wrow = (int)(vlow >> 13), wcode = (int)(vlow & 8191u);
    int lo = tid * (NROWS / 256);
    int hi = lo + (NROWS / 256); if (hi > wrow) hi = wrow;
    int cnt = 0;
#pragma unroll 4
    for (int i = lo; i < hi; ++i) cnt += (mask[i] != 0);
    __shared__ int ps[256];
    ps[tid] = cnt;
    __syncthreads();
    for (int s = 128; s > 0; s >>= 1) {
      if (tid < s) ps[tid] += ps[tid + s];
      __syncthreads();
    }
    if (tid == 0) out[0] = ps[0] * NCODES + wcode;  // rank*8192 + code
  }
}

extern "C" void kernel_launch(void* const* d_in, const int* in_sizes, int n_in,
                              void* d_out, int out_size, void* d_ws, size_t ws_size,
                              hipStream_t stream) {
  const float* x    = (const float*)d_in[0];
  const int*   mask = (const int*)d_in[1];
  const float* W    = (const float*)d_in[2];
  const float* cbk  = (const float*)d_in[3];
  int* out = (int*)d_out;

  char* ws = (char*)d_ws;                            // total 1,843,200 B (proven < ws_size)
  unsigned int*       ctrs      = (unsigned int*)(ws + 4096);
  unsigned int*       slotctr   = (unsigned int*)(ws + 4096);
  unsigned int*       resctr    = (unsigned int*)(ws + 4100);
  unsigned int*       candcount = (unsigned int*)(ws + 4112);       // gatecp stores
  unsigned long long* key       = (unsigned long long*)(ws + 8184); // init
  unsigned int*       rowmin_u  = (unsigned int*)(ws + 8192);       // 64 KiB (project inits)
  float*              t2arr     = (float*)(ws + 73728);             // 64 KiB
  int*                origrow   = (int*)(ws + 139264);              // 64 KiB
  float*              c2        = (float*)(ws + 204800);            // 32 KiB
  unsigned int*       cnrm      = (unsigned int*)(ws + 237568);     // 32 KiB
  unsigned short*     cbf32     = (unsigned short*)(ws + 270336);   // 512 KiB
  int*                candlist  = (int*)(ws + 270336);              // aliases cbf32 (dead by gate)
  unsigned short*     tbf32     = (unsigned short*)(ws + 794624);   // 1 MiB
  float*              tgtm      = (float*)(ws + 794624);            // aliases tbf32 (dead after phase1)

  init_kernel<<<1, 64, 0, stream>>>(ctrs, key);
  project_kernel<<<256, 256, 0, stream>>>(x, mask, W, cbk, c2, cnrm, cbf32,
                                          tbf32, t2arr, origrow, rowmin_u, slotctr);
  phase1_kernel<<<2048, 256, 0, stream>>>(tbf32, cbf32, cnrm, t2arr, rowmin_u);
  gatecp_kernel<<<1, 1024, 0, stream>>>(x, W, c2, t2arr, origrow, rowmin_u,
                                        candcount, candlist, tgtm);
  rescore_kernel<<<512, 256, 0, stream>>>(cbk, c2, tgtm, t2arr, origrow, mask,
                                          candcount, candlist, key, resctr, out);
}

// Round 21
// 96.932 us; speedup vs baseline: 1.4930x; 1.4930x over previous
//
#include <hip/hip_runtime.h>
#include <hip/hip_bf16.h>

// RandomProjectionQuantizer — R21: R14 (best measured, 89.4us) + paired project.
//  x:(16,2048,320) f32, mask:(16,2048) i32 (exactly 16384 ones),
//  W:(16,320) f32, codebook:(8192,16) f32 -> scalar int32 label
//
//  init    : counters + key (R14-verbatim).
//  project : 256 blocks x 256, block = 128 rows; pos[] rank table (R20-proven);
//            pair-path = 2 rows/thread sharing W LDS-reads (R20-proven,
//            bit-identical per-row chains); R14 fold data formats
//            (tbf=[t,1,1,h1,h2,0..], cbf=[-2c,g1,g2,1,1,0..]); rowmin init.
//  phase1  : R14-verbatim 1-MFMA fold screen (2048 x 256, strip/seg, LDS merge
//            + global atomicMin).
//  gate    : R14-verbatim lean (1 x 1024).
//  cproj   : R14-verbatim (512 blocks, LDS-W, early-exit).
//  rescore : R14-verbatim (512 blocks, u64 atomicMin + ticket + rank emit).

#define NMASK   16384
#define NROWS   32768
#define D       320
#define CDIM    16
#define NCODES  8192
#define EPS_C   0.0117f      // 1.5 * 2^-7  (bf16 RNE dot-error coefficient)
#define EPS_ABS 0.02f

typedef __attribute__((ext_vector_type(8))) short short8;
typedef __attribute__((ext_vector_type(4))) float f32x4;

__device__ inline unsigned int encf(float f) {
  unsigned int u = __float_as_uint(f);
  return (u & 0x80000000u) ? ~u : (u | 0x80000000u);
}
__device__ inline float decf(unsigned int u) {
  unsigned int b = (u & 0x80000000u) ? (u & 0x7fffffffu) : ~u;
  return __uint_as_float(b);
}
__device__ inline unsigned short f2bf(float f) {   // RNE f32->bf16
  unsigned int u = __float_as_uint(f);
  unsigned int r = u + 0x7fffu + ((u >> 16) & 1u);
  return (unsigned short)(r >> 16);
}
__device__ inline float bf2f(unsigned short h) {
  return __uint_as_float(((unsigned int)h) << 16);
}

// LDS-W projection body (R12/R14-proven): lane ch covers d in {j*32+ch*4..+4},
// x prefetched (10-deep MLP), butterfly combine (xor 1,2,4).
__device__ inline void proj_lds(const float* __restrict__ x,
                                const float* __restrict__ Wl,
                                int row, int ch, float pd[16]) {
  const float* xr = x + (size_t)row * D + ch * 4;
  float4 xv[10];
#pragma unroll
  for (int j = 0; j < 10; ++j) xv[j] = *(const float4*)(xr + j * 32);
#pragma unroll
  for (int c = 0; c < 16; ++c) pd[c] = 0.f;
#pragma unroll
  for (int j = 0; j < 10; ++j) {
#pragma unroll
    for (int c = 0; c < 16; ++c) {
      const float4 wv = *(const float4*)&Wl[c * D + j * 32 + ch * 4];
      float acc = fmaf(xv[j].x, wv.x, pd[c]);
      acc = fmaf(xv[j].y, wv.y, acc);
      acc = fmaf(xv[j].z, wv.z, acc);
      pd[c] = fmaf(xv[j].w, wv.w, acc);
    }
  }
#pragma unroll
  for (int c = 0; c < 16; ++c) {
    pd[c] += __shfl_xor(pd[c], 1);
    pd[c] += __shfl_xor(pd[c], 2);
    pd[c] += __shfl_xor(pd[c], 4);
  }
}

// store projected row in R14 FOLD format: tbf[slot][32]=[t_bf16(16),1,1,h1,h2,0..]
__device__ inline void store_t(const float pd[16], int slot, int row,
                               float* __restrict__ t2arr,
                               int* __restrict__ origrow,
                               unsigned short* __restrict__ tbf32) {
  float t2 = 0.f;
#pragma unroll
  for (int c = 0; c < 16; ++c) t2 = fmaf(pd[c], pd[c], t2);
  t2arr[slot] = t2;
  origrow[slot] = row;
  unsigned short tb[16];
#pragma unroll
  for (int c = 0; c < 16; ++c) tb[c] = f2bf(pd[c]);
  unsigned short h1 = f2bf(t2);
  unsigned short h2 = f2bf(t2 - bf2f(h1));
  uint4 pk0, pk1, pk2, pk3;
  pk0.x = (unsigned int)tb[0]  | ((unsigned int)tb[1]  << 16);
  pk0.y = (unsigned int)tb[2]  | ((unsigned int)tb[3]  << 16);
  pk0.z = (unsigned int)tb[4]  | ((unsigned int)tb[5]  << 16);
  pk0.w = (unsigned int)tb[6]  | ((unsigned int)tb[7]  << 16);
  pk1.x = (unsigned int)tb[8]  | ((unsigned int)tb[9]  << 16);
  pk1.y = (unsigned int)tb[10] | ((unsigned int)tb[11] << 16);
  pk1.z = (unsigned int)tb[12] | ((unsigned int)tb[13] << 16);
  pk1.w = (unsigned int)tb[14] | ((unsigned int)tb[15] << 16);
  pk2.x = 0x3F803F80u;                                 // dims 16,17: 1,1
  pk2.y = (unsigned int)h1 | ((unsigned int)h2 << 16); // dims 18,19: h1,h2
  pk2.z = 0u; pk2.w = 0u;
  pk3.x = 0u; pk3.y = 0u; pk3.z = 0u; pk3.w = 0u;
  uint4* dst = (uint4*)(tbf32 + (long)slot * 32);
  dst[0] = pk0; dst[1] = pk1; dst[2] = pk2; dst[3] = pk3;
}

// ---------------- Kernel 0: init (1 block x 64, R14-verbatim) ----------------
__global__ void init_kernel(unsigned int* __restrict__ ctrs,
                            unsigned long long* __restrict__ key) {
  if (threadIdx.x < 4) ctrs[threadIdx.x] = 0u;      // slotctr, resctr (+spare)
  if (threadIdx.x == 4) key[0] = 0xFFFFFFFFFFFFFFFFull;
}

// ---------------- Kernel 1: project (256 blocks x 256) -----------------------
__global__ __launch_bounds__(256) void project_kernel(
    const float* __restrict__ x, const int* __restrict__ mask,
    const float* __restrict__ W, const float* __restrict__ cbk,
    float* __restrict__ c2, unsigned short* __restrict__ cbf32,
    unsigned short* __restrict__ tbf32, float* __restrict__ t2arr,
    int* __restrict__ origrow, unsigned int* __restrict__ rowmin_u,
    unsigned int* __restrict__ slotctr) {
  __shared__ float Wl[CDIM * D];                    // 20 KiB
  __shared__ unsigned long long mbs[2];
  __shared__ int pos[128];
  __shared__ unsigned int base_s;
  int tid = threadIdx.x, bid = (int)blockIdx.x;
  int rbase = bid * 128;
  for (int i = tid; i < (CDIM * D) / 4; i += 256)
    ((float4*)Wl)[i] = ((const float4*)W)[i];
  if (tid < 128) {                                  // waves 0,1: ballots
    int m = mask[rbase + tid];
    unsigned long long bal = __ballot(m != 0);
    if ((tid & 63) == 0) mbs[tid >> 6] = bal;
  }
  if (tid < 64) rowmin_u[bid * 64 + tid] = 0xFFFFFFFFu;   // 256*64 = 16384
  __syncthreads();

  if (tid < 32) {                                   // codes job (R14 fold fmt)
    int k = bid * 32 + tid;                         // 256*32 = 8192
    const float4* p = (const float4*)(cbk + (long)k * CDIM);
    float s = 0.f; unsigned short nb[16];
#pragma unroll
    for (int q = 0; q < 4; ++q) {
      float4 v = p[q];
      s = fmaf(v.x, v.x, s); s = fmaf(v.y, v.y, s);
      s = fmaf(v.z, v.z, s); s = fmaf(v.w, v.w, s);
      nb[q*4+0] = f2bf(-2.0f * v.x); nb[q*4+1] = f2bf(-2.0f * v.y);
      nb[q*4+2] = f2bf(-2.0f * v.z); nb[q*4+3] = f2bf(-2.0f * v.w);
    }
    c2[k] = s;
    unsigned short g1 = f2bf(s);
    unsigned short g2 = f2bf(s - bf2f(g1));
    uint4 pk0, pk1, pk2, pk3;
    pk0.x = (unsigned int)nb[0]  | ((unsigned int)nb[1]  << 16);
    pk0.y = (unsigned int)nb[2]  | ((unsigned int)nb[3]  << 16);
    pk0.z = (unsigned int)nb[4]  | ((unsigned int)nb[5]  << 16);
    pk0.w = (unsigned int)nb[6]  | ((unsigned int)nb[7]  << 16);
    pk1.x = (unsigned int)nb[8]  | ((unsigned int)nb[9]  << 16);
    pk1.y = (unsigned int)nb[10] | ((unsigned int)nb[11] << 16);
    pk1.z = (unsigned int)nb[12] | ((unsigned int)nb[13] << 16);
    pk1.w = (unsigned int)nb[14] | ((unsigned int)nb[15] << 16);
    pk2.x = (unsigned int)g1 | ((unsigned int)g2 << 16); // dims 16,17: g1,g2
    pk2.y = 0x3F803F80u;                                 // dims 18,19: 1,1
    pk2.z = 0u; pk2.w = 0u;
    pk3.x = 0u; pk3.y = 0u; pk3.z = 0u; pk3.w = 0u;
    uint4* dst = (uint4*)(cbf32 + (long)k * 32);
    dst[0] = pk0; dst[1] = pk1; dst[2] = pk2; dst[3] = pk3;
  }

  unsigned long long B0 = mbs[0], B1 = mbs[1];
  int cnt0 = __popcll(B0);
  int cnt  = cnt0 + __popcll(B1);
  if (tid < 64 && ((B0 >> tid) & 1ull))
    pos[__popcll(B0 & ((1ull << tid) - 1ull))] = tid;
  if (tid >= 64 && tid < 128 && ((B1 >> (tid - 64)) & 1ull))
    pos[cnt0 + __popcll(B1 & ((1ull << (tid - 64)) - 1ull))] = tid;
  if (tid == 0) base_s = cnt ? atomicAdd(slotctr, (unsigned int)cnt) : 0u;
  __syncthreads();
  unsigned int base = base_s;

  int r = tid >> 3, ch = tid & 7;
  int idx0 = r, idx1 = r + 32;
  if (idx1 < cnt) {                                 // pair path (R20-proven)
    int row0 = rbase + pos[idx0], row1 = rbase + pos[idx1];
    const float* xr0 = x + (size_t)row0 * D + ch * 4;
    const float* xr1 = x + (size_t)row1 * D + ch * 4;
    float4 xv0[10], xv1[10];
#pragma unroll
    for (int j = 0; j < 10; ++j) { xv0[j] = *(const float4*)(xr0 + j * 32);
                                   xv1[j] = *(const float4*)(xr1 + j * 32); }
    float pd0[16], pd1[16];
#pragma unroll
    for (int c = 0; c < 16; ++c) { pd0[c] = 0.f; pd1[c] = 0.f; }
#pragma unroll
    for (int j = 0; j < 10; ++j) {
#pragma unroll
      for (int c = 0; c < 16; ++c) {                // shared W read, 2 rows
        const float4 wv = *(const float4*)&Wl[c * D + j * 32 + ch * 4];
        float a0 = fmaf(xv0[j].x, wv.x, pd0[c]);
        a0 = fmaf(xv0[j].y, wv.y, a0);
        a0 = fmaf(xv0[j].z, wv.z, a0);
        pd0[c] = fmaf(xv0[j].w, wv.w, a0);
        float a1 = fmaf(xv1[j].x, wv.x, pd1[c]);
        a1 = fmaf(xv1[j].y, wv.y, a1);
        a1 = fmaf(xv1[j].z, wv.z, a1);
        pd1[c] = fmaf(xv1[j].w, wv.w, a1);
      }
    }
#pragma unroll
    for (int c = 0; c < 16; ++c) {
      pd0[c] += __shfl_xor(pd0[c], 1);
      pd0[c] += __shfl_xor(pd0[c], 2);
      pd0[c] += __shfl_xor(pd0[c], 4);
    }
#pragma unroll
    for (int c = 0; c < 16; ++c) {
      pd1[c] += __shfl_xor(pd1[c], 1);
      pd1[c] += __shfl_xor(pd1[c], 2);
      pd1[c] += __shfl_xor(pd1[c], 4);
    }
    if (ch == 0) {
      store_t(pd0, (int)base + idx0, row0, t2arr, origrow, tbf32);
      store_t(pd1, (int)base + idx1, row1, t2arr, origrow, tbf32);
    }
  } else if (idx0 < cnt) {                          // single tail
    int row = rbase + pos[idx0];
    float pd[16];
    proj_lds(x, Wl, row, ch, pd);
    if (ch == 0) store_t(pd, (int)base + idx0, row, t2arr, origrow, tbf32);
  }
  for (int idx = r + 64; idx < cnt; idx += 32) {    // overflow ranks (rare)
    int row = rbase + pos[idx];
    float pd[16];
    proj_lds(x, Wl, row, ch, pd);
    if (ch == 0) store_t(pd, (int)base + idx, row, t2arr, origrow, tbf32);
  }
}

// ---------------- Kernel 2: MFMA fold screening (2048 x 256, R14-verbatim) ---
__global__ __launch_bounds__(256) void phase1_kernel(
    const unsigned short* __restrict__ tbf32,
    const unsigned short* __restrict__ cbf32,
    unsigned int* __restrict__ rowmin_u) {
  __shared__ unsigned int rml[4 * 33];
  int tid = threadIdx.x;
  int w = tid >> 6, l = tid & 63, lr = l & 15, g = l >> 4;
  int strip = (int)blockIdx.x >> 2;                 // 0..511
  int seg   = ((int)blockIdx.x & 3) * 4 + w;        // 0..15
  int row0 = strip * 32;

  for (int i = tid; i < 4 * 33; i += 256) rml[i] = 0xFFFFFFFFu;
  __syncthreads();

  const f32x4 zero = {0.f, 0.f, 0.f, 0.f};
  short8 calA = {0,0,0,0,0,0,0,0}, calB = {0,0,0,0,0,0,0,0};
  if (g == 0) {
    calA[0] = (short)f2bf((float)(lr + 1));
    calB[0] = (short)0x3F80;                        // bf16 1.0
  }
  f32x4 cal = __builtin_amdgcn_mfma_f32_16x16x32_bf16(calA, calB, zero, 0, 0, 0);
  int rid[4];
#pragma unroll
  for (int j = 0; j < 4; ++j) {
    int v = (int)(cal[j] + 0.5f) - 1;
    rid[j] = v < 0 ? 0 : (v > 15 ? 15 : v);
  }

  const short8 a0 = *(const short8*)(tbf32 + (long)(row0 + lr) * 32 + g * 8);
  const short8 a1 = *(const short8*)(tbf32 + (long)(row0 + 16 + lr) * 32 + g * 8);
  f32x4 rmin0 = {3.4e38f, 3.4e38f, 3.4e38f, 3.4e38f};
  f32x4 rmin1 = rmin0;
  int code0 = seg * 512;
#pragma unroll 2
  for (int t = 0; t < 32; ++t) {
    int code = code0 + t * 16 + lr;
    short8 b = *(const short8*)(cbf32 + (long)code * 32 + g * 8);
    f32x4 d0 = __builtin_amdgcn_mfma_f32_16x16x32_bf16(a0, b, zero, 0, 0, 0);
    f32x4 d1 = __builtin_amdgcn_mfma_f32_16x16x32_bf16(a1, b, zero, 0, 0, 0);
#pragma unroll
    for (int j = 0; j < 4; ++j) {
      rmin0[j] = fminf(rmin0[j], d0[j]);
      rmin1[j] = fminf(rmin1[j], d1[j]);
    }
  }
  unsigned int* mywave = &rml[w * 33];
#pragma unroll
  for (int j = 0; j < 4; ++j) {
    atomicMin(&mywave[rid[j]],      encf(rmin0[j]));
    atomicMin(&mywave[16 + rid[j]], encf(rmin1[j]));
  }
  __syncthreads();
  if (tid < 32) {
    unsigned int mn = 0xFFFFFFFFu;
#pragma unroll
    for (int ww = 0; ww < 4; ++ww) mn = min(mn, rml[ww * 33 + tid]);
    atomicMin(&rowmin_u[row0 + tid], mn);
  }
}

// ---------------- Kernel 3: gate (1 block x 1024, R14-verbatim) --------------
__global__ __launch_bounds__(1024) void gate_kernel(
    const unsigned int* __restrict__ rowmin_u, const float* __restrict__ t2arr,
    const float* __restrict__ c2,
    unsigned int* __restrict__ candcount, int* __restrict__ candlist) {
  __shared__ float red_f[1024];
  __shared__ float c2m_s;
  __shared__ unsigned int cnt;
  int tid = threadIdx.x;
  float cm = 0.f;                                   // c2 >= 0
#pragma unroll
  for (int i = 0; i < 8; ++i) cm = fmaxf(cm, c2[tid + i * 1024]);
  red_f[tid] = cm;
  if (tid == 0) cnt = 0u;
  __syncthreads();
  for (int st = 512; st > 0; st >>= 1) {
    if (tid < st) red_f[tid] = fmaxf(red_f[tid], red_f[tid + st]);
    __syncthreads();
  }
  if (tid == 0) c2m_s = red_f[0];
  __syncthreads();
  float c2m = c2m_s;
  float Tl = 3.4e38f;
  for (int i = tid; i < NMASK; i += 1024) {
    float a = decf(rowmin_u[i]);
    float e = fmaf(EPS_C, sqrtf(t2arr[i] * c2m), EPS_ABS);
    Tl = fminf(Tl, a + e);                          // NaN -> ignored
  }
  red_f[tid] = Tl;
  __syncthreads();
  for (int st = 512; st > 0; st >>= 1) {
    if (tid < st) red_f[tid] = fminf(red_f[tid], red_f[tid + st]);
    __syncthreads();
  }
  float T = red_f[0];
  for (int i = tid; i < NMASK; i += 1024) {
    float a = decf(rowmin_u[i]);
    float e = fmaf(EPS_C, sqrtf(t2arr[i] * c2m), EPS_ABS);
    if (!(a - e > T)) {                             // NaN-safe: NaN -> candidate
      unsigned int pos = atomicAdd(&cnt, 1u);
      candlist[pos] = i;
    }
  }
  __syncthreads();
  if (tid == 0) candcount[0] = cnt;                 // plain store
}

// ---------------- Kernel 4: cproj (512 x 256, R14-verbatim) ------------------
__global__ __launch_bounds__(256) void cproj_kernel(
    const float* __restrict__ x, const float* __restrict__ W,
    const int* __restrict__ origrow, const unsigned int* __restrict__ candcount,
    const int* __restrict__ candlist, float* __restrict__ tgtm) {
  int tid = threadIdx.x, bid = (int)blockIdx.x;
  int nc = (int)candcount[0];
  if (bid * 32 >= nc) return;                       // whole block idle
  __shared__ float Wl[CDIM * D];                    // 20 KiB
  for (int i = tid; i < (CDIM * D) / 4; i += 256)
    ((float4*)Wl)[i] = ((const float4*)W)[i];
  __syncthreads();
  int idx = bid * 32 + (tid >> 3);                  // candidate index
  int ch  = tid & 7;
  if (idx >= nc) return;
  int row = origrow[candlist[idx]];
  float pd[16];
  proj_lds(x, Wl, row, ch, pd);                     // bit-identical chain
  if (ch == 0) {
    float* op = tgtm + (long)idx * 16;
#pragma unroll
    for (int c = 0; c < 16; ++c) op[c] = -2.0f * pd[c];
  }
}

// ---------------- Kernel 5: rescore + rank emit (512 x 256, R14-verbatim) ----
__global__ __launch_bounds__(256) void rescore_kernel(
    const float* __restrict__ cbk, const float* __restrict__ c2,
    const float* __restrict__ tgtm, const float* __restrict__ t2arr,
    const int* __restrict__ origrow, const int* __restrict__ mask,
    const unsigned int* __restrict__ candcount, const int* __restrict__ candlist,
    unsigned long long* __restrict__ key, unsigned int* __restrict__ resctr,
    int* __restrict__ out) {
  __shared__ unsigned long long red[256];
  __shared__ int lastf;
  __shared__ unsigned int vlow_s;
  int tid = threadIdx.x, bid = (int)blockIdx.x;
  int nwork = (int)candcount[0] * 8;                // 8 octants x 1024 codes
  for (int wk = bid; wk < nwork; wk += (int)gridDim.x) {
    int ci = wk >> 3, oct = wk & 7;
    int r = candlist[ci];                           // slot, uniform per block
    float t2 = t2arr[r];
    int row = origrow[r];
    float tm[16];
    const float4* tp = (const float4*)(tgtm + (long)ci * 16);
#pragma unroll
    for (int q = 0; q < 4; ++q) {                   // uniform -> scalar loads
      float4 v = tp[q];
      tm[q*4+0] = v.x; tm[q*4+1] = v.y; tm[q*4+2] = v.z; tm[q*4+3] = v.w;
    }
    float minv = 3.4e38f; int mink = 0;
#pragma unroll 2
    for (int k = 0; k < 4; ++k) {                   // 4 codes/thread
      int code = oct * 1024 + k * 256 + tid;
      const float4* cp = (const float4*)(cbk + (long)code * CDIM);
      float4 c0 = cp[0], c1 = cp[1], c2v4 = cp[2], c3 = cp[3];
      float acc = fmaf(tm[0],  c0.x, c2[code]);
      acc = fmaf(tm[1],  c0.y, acc);   acc = fmaf(tm[2],  c0.z, acc);
      acc = fmaf(tm[3],  c0.w, acc);   acc = fmaf(tm[4],  c1.x, acc);
      acc = fmaf(tm[5],  c1.y, acc);   acc = fmaf(tm[6],  c1.z, acc);
      acc = fmaf(tm[7],  c1.w, acc);   acc = fmaf(tm[8],  c2v4.x, acc);
      acc = fmaf(tm[9],  c2v4.y, acc); acc = fmaf(tm[10], c2v4.z, acc);
      acc = fmaf(tm[11], c2v4.w, acc); acc = fmaf(tm[12], c3.x, acc);
      acc = fmaf(tm[13], c3.y, acc);   acc = fmaf(tm[14], c3.z, acc);
      acc = fmaf(tm[15], c3.w, acc);
      if (acc < minv) { minv = acc; mink = code; }
    }
    // tie-break on row*8192+code == lexicographic (row, code) == rank order
    red[tid] = ((unsigned long long)encf(t2 + minv) << 32)
        | (unsigned long long)((unsigned int)row * (unsigned int)NCODES + (unsigned int)mink);
    __syncthreads();
    for (int s = 128; s > 0; s >>= 1) {
      if (tid < s) { if (red[tid + s] < red[tid]) red[tid] = red[tid + s]; }
      __syncthreads();
    }
    if (tid == 0) atomicMin(key, red[0]);
    __syncthreads();                                // LDS reuse across wk
  }
  if (tid == 0) {
    __threadfence();
    lastf = (atomicAdd(resctr, 1u) == (unsigned int)gridDim.x - 1u) ? 1 : 0;
  }
  __syncthreads();
  if (lastf) {                                      // last block: rank + emit
    if (tid == 0)
      vlow_s = (unsigned int)(atomicMin(key, 0xFFFFFFFFFFFFFFFFull) & 0xFFFFFFFFull);
    __syncthreads();
    unsigned int vlow = vlow_s;
    int wrow = (int)(vlow >> 13), wcode = (int)(vlow & 8191u);
    int lo = tid * (NROWS / 256);
    int hi = lo + (NROWS / 256); if (hi > wrow) hi = wrow;
    int cnt = 0;
#pragma unroll 4
    for (int i = lo; i < hi; ++i) cnt += (mask[i] != 0);
    __shared__ int ps[256];
    ps[tid] = cnt;
    __syncthreads();
    for (int s = 128; s > 0; s >>= 1) {
      if (tid < s) ps[tid] += ps[tid + s];
      __syncthreads();
    }
    if (tid == 0) out[0] = ps[0] * NCODES + wcode;  // rank*8192 + code
  }
}

extern "C" void kernel_launch(void* const* d_in, const int* in_sizes, int n_in,
                              void* d_out, int out_size, void* d_ws, size_t ws_size,
                              hipStream_t stream) {
  const float* x    = (const float*)d_in[0];
  const int*   mask = (const int*)d_in[1];
  const float* W    = (const float*)d_in[2];
  const float* cbk  = (const float*)d_in[3];
  int* out = (int*)d_out;

  char* ws = (char*)d_ws;                                   // total 1,810,432 B (R14-proven)
  unsigned int*       ctrs      = (unsigned int*)(ws + 4096);
  unsigned int*       slotctr   = (unsigned int*)(ws + 4096);
  unsigned int*       resctr    = (unsigned int*)(ws + 4100);
  unsigned int*       candcount = (unsigned int*)(ws + 4112);       // gate stores
  unsigned long long* key       = (unsigned long long*)(ws + 8184); // init
  unsigned int*       rowmin_u  = (unsigned int*)(ws + 8192);       // 64 KiB (project inits)
  float*              t2arr     = (float*)(ws + 73728);             // 64 KiB
  int*                origrow   = (int*)(ws + 139264);              // 64 KiB
  float*              c2        = (float*)(ws + 204800);            // 32 KiB
  unsigned short*     cbf32     = (unsigned short*)(ws + 237568);   // 512 KiB
  int*                candlist  = (int*)(ws + 237568);              // aliases cbf32 (dead by gate)
  unsigned short*     tbf32     = (unsigned short*)(ws + 761856);   // 1 MiB
  float*              tgtm      = (float*)(ws + 761856);            // aliases tbf32 (dead after phase1)

  init_kernel<<<1, 64, 0, stream>>>(ctrs, key);
  project_kernel<<<256, 256, 0, stream>>>(x, mask, W, cbk, c2, cbf32, tbf32,
                                          t2arr, origrow, rowmin_u, slotctr);
  phase1_kernel<<<2048, 256, 0, stream>>>(tbf32, cbf32, rowmin_u);
  gate_kernel<<<1, 1024, 0, stream>>>(rowmin_u, t2arr, c2, candcount, candlist);
  cproj_kernel<<<512, 256, 0, stream>>>(x, W, origrow, candcount, candlist, tgtm);
  rescore_kernel<<<512, 256, 0, stream>>>(cbk, c2, tgtm, t2arr, origrow, mask,
                                          candcount, candlist, key, resctr, out);
}

// Round 22
// 92.912 us; speedup vs baseline: 1.5576x; 1.0433x over previous
//
#include <hip/hip_runtime.h>
#include <hip/hip_bf16.h>

// RandomProjectionQuantizer — R22: R21 with de-spilled pair-path project.
//  x:(16,2048,320) f32, mask:(16,2048) i32 (exactly 16384 ones),
//  W:(16,320) f32, codebook:(8192,16) f32 -> scalar int32 label
//
//  R21's pair path hit VGPR=256 (twin 10-float4 prefetch) -> spill, 41us.
//  R22: load x inside the j-loop (2 loads/iter, unroll 2) -> ~110 VGPR.
//  FP math and order bit-identical (only load placement changed).
//  All other kernels R14/R21-verbatim (proven).

#define NMASK   16384
#define NROWS   32768
#define D       320
#define CDIM    16
#define NCODES  8192
#define EPS_C   0.0117f      // 1.5 * 2^-7  (bf16 RNE dot-error coefficient)
#define EPS_ABS 0.02f

typedef __attribute__((ext_vector_type(8))) short short8;
typedef __attribute__((ext_vector_type(4))) float f32x4;

__device__ inline unsigned int encf(float f) {
  unsigned int u = __float_as_uint(f);
  return (u & 0x80000000u) ? ~u : (u | 0x80000000u);
}
__device__ inline float decf(unsigned int u) {
  unsigned int b = (u & 0x80000000u) ? (u & 0x7fffffffu) : ~u;
  return __uint_as_float(b);
}
__device__ inline unsigned short f2bf(float f) {   // RNE f32->bf16
  unsigned int u = __float_as_uint(f);
  unsigned int r = u + 0x7fffu + ((u >> 16) & 1u);
  return (unsigned short)(r >> 16);
}
__device__ inline float bf2f(unsigned short h) {
  return __uint_as_float(((unsigned int)h) << 16);
}

// LDS-W projection body (R12/R14-proven): lane ch covers d in {j*32+ch*4..+4},
// x prefetched (10-deep MLP), butterfly combine (xor 1,2,4).
__device__ inline void proj_lds(const float* __restrict__ x,
                                const float* __restrict__ Wl,
                                int row, int ch, float pd[16]) {
  const float* xr = x + (size_t)row * D + ch * 4;
  float4 xv[10];
#pragma unroll
  for (int j = 0; j < 10; ++j) xv[j] = *(const float4*)(xr + j * 32);
#pragma unroll
  for (int c = 0; c < 16; ++c) pd[c] = 0.f;
#pragma unroll
  for (int j = 0; j < 10; ++j) {
#pragma unroll
    for (int c = 0; c < 16; ++c) {
      const float4 wv = *(const float4*)&Wl[c * D + j * 32 + ch * 4];
      float acc = fmaf(xv[j].x, wv.x, pd[c]);
      acc = fmaf(xv[j].y, wv.y, acc);
      acc = fmaf(xv[j].z, wv.z, acc);
      pd[c] = fmaf(xv[j].w, wv.w, acc);
    }
  }
#pragma unroll
  for (int c = 0; c < 16; ++c) {
    pd[c] += __shfl_xor(pd[c], 1);
    pd[c] += __shfl_xor(pd[c], 2);
    pd[c] += __shfl_xor(pd[c], 4);
  }
}

// store projected row in R14 FOLD format: tbf[slot][32]=[t_bf16(16),1,1,h1,h2,0..]
__device__ inline void store_t(const float pd[16], int slot, int row,
                               float* __restrict__ t2arr,
                               int* __restrict__ origrow,
                               unsigned short* __restrict__ tbf32) {
  float t2 = 0.f;
#pragma unroll
  for (int c = 0; c < 16; ++c) t2 = fmaf(pd[c], pd[c], t2);
  t2arr[slot] = t2;
  origrow[slot] = row;
  unsigned short tb[16];
#pragma unroll
  for (int c = 0; c < 16; ++c) tb[c] = f2bf(pd[c]);
  unsigned short h1 = f2bf(t2);
  unsigned short h2 = f2bf(t2 - bf2f(h1));
  uint4 pk0, pk1, pk2, pk3;
  pk0.x = (unsigned int)tb[0]  | ((unsigned int)tb[1]  << 16);
  pk0.y = (unsigned int)tb[2]  | ((unsigned int)tb[3]  << 16);
  pk0.z = (unsigned int)tb[4]  | ((unsigned int)tb[5]  << 16);
  pk0.w = (unsigned int)tb[6]  | ((unsigned int)tb[7]  << 16);
  pk1.x = (unsigned int)tb[8]  | ((unsigned int)tb[9]  << 16);
  pk1.y = (unsigned int)tb[10] | ((unsigned int)tb[11] << 16);
  pk1.z = (unsigned int)tb[12] | ((unsigned int)tb[13] << 16);
  pk1.w = (unsigned int)tb[14] | ((unsigned int)tb[15] << 16);
  pk2.x = 0x3F803F80u;                                 // dims 16,17: 1,1
  pk2.y = (unsigned int)h1 | ((unsigned int)h2 << 16); // dims 18,19: h1,h2
  pk2.z = 0u; pk2.w = 0u;
  pk3.x = 0u; pk3.y = 0u; pk3.z = 0u; pk3.w = 0u;
  uint4* dst = (uint4*)(tbf32 + (long)slot * 32);
  dst[0] = pk0; dst[1] = pk1; dst[2] = pk2; dst[3] = pk3;
}

// ---------------- Kernel 0: init (1 block x 64, R14-verbatim) ----------------
__global__ void init_kernel(unsigned int* __restrict__ ctrs,
                            unsigned long long* __restrict__ key) {
  if (threadIdx.x < 4) ctrs[threadIdx.x] = 0u;      // slotctr, resctr (+spare)
  if (threadIdx.x == 4) key[0] = 0xFFFFFFFFFFFFFFFFull;
}

// ---------------- Kernel 1: project (256 blocks x 256) -----------------------
__global__ __launch_bounds__(256) void project_kernel(
    const float* __restrict__ x, const int* __restrict__ mask,
    const float* __restrict__ W, const float* __restrict__ cbk,
    float* __restrict__ c2, unsigned short* __restrict__ cbf32,
    unsigned short* __restrict__ tbf32, float* __restrict__ t2arr,
    int* __restrict__ origrow, unsigned int* __restrict__ rowmin_u,
    unsigned int* __restrict__ slotctr) {
  __shared__ float Wl[CDIM * D];                    // 20 KiB
  __shared__ unsigned long long mbs[2];
  __shared__ int pos[128];
  __shared__ unsigned int base_s;
  int tid = threadIdx.x, bid = (int)blockIdx.x;
  int rbase = bid * 128;
  for (int i = tid; i < (CDIM * D) / 4; i += 256)
    ((float4*)Wl)[i] = ((const float4*)W)[i];
  if (tid < 128) {                                  // waves 0,1: ballots
    int m = mask[rbase + tid];
    unsigned long long bal = __ballot(m != 0);
    if ((tid & 63) == 0) mbs[tid >> 6] = bal;
  }
  if (tid < 64) rowmin_u[bid * 64 + tid] = 0xFFFFFFFFu;   // 256*64 = 16384
  __syncthreads();

  if (tid < 32) {                                   // codes job (R14 fold fmt)
    int k = bid * 32 + tid;                         // 256*32 = 8192
    const float4* p = (const float4*)(cbk + (long)k * CDIM);
    float s = 0.f; unsigned short nb[16];
#pragma unroll
    for (int q = 0; q < 4; ++q) {
      float4 v = p[q];
      s = fmaf(v.x, v.x, s); s = fmaf(v.y, v.y, s);
      s = fmaf(v.z, v.z, s); s = fmaf(v.w, v.w, s);
      nb[q*4+0] = f2bf(-2.0f * v.x); nb[q*4+1] = f2bf(-2.0f * v.y);
      nb[q*4+2] = f2bf(-2.0f * v.z); nb[q*4+3] = f2bf(-2.0f * v.w);
    }
    c2[k] = s;
    unsigned short g1 = f2bf(s);
    unsigned short g2 = f2bf(s - bf2f(g1));
    uint4 pk0, pk1, pk2, pk3;
    pk0.x = (unsigned int)nb[0]  | ((unsigned int)nb[1]  << 16);
    pk0.y = (unsigned int)nb[2]  | ((unsigned int)nb[3]  << 16);
    pk0.z = (unsigned int)nb[4]  | ((unsigned int)nb[5]  << 16);
    pk0.w = (unsigned int)nb[6]  | ((unsigned int)nb[7]  << 16);
    pk1.x = (unsigned int)nb[8]  | ((unsigned int)nb[9]  << 16);
    pk1.y = (unsigned int)nb[10] | ((unsigned int)nb[11] << 16);
    pk1.z = (unsigned int)nb[12] | ((unsigned int)nb[13] << 16);
    pk1.w = (unsigned int)nb[14] | ((unsigned int)nb[15] << 16);
    pk2.x = (unsigned int)g1 | ((unsigned int)g2 << 16); // dims 16,17: g1,g2
    pk2.y = 0x3F803F80u;                                 // dims 18,19: 1,1
    pk2.z = 0u; pk2.w = 0u;
    pk3.x = 0u; pk3.y = 0u; pk3.z = 0u; pk3.w = 0u;
    uint4* dst = (uint4*)(cbf32 + (long)k * 32);
    dst[0] = pk0; dst[1] = pk1; dst[2] = pk2; dst[3] = pk3;
  }

  unsigned long long B0 = mbs[0], B1 = mbs[1];
  int cnt0 = __popcll(B0);
  int cnt  = cnt0 + __popcll(B1);
  if (tid < 64 && ((B0 >> tid) & 1ull))
    pos[__popcll(B0 & ((1ull << tid) - 1ull))] = tid;
  if (tid >= 64 && tid < 128 && ((B1 >> (tid - 64)) & 1ull))
    pos[cnt0 + __popcll(B1 & ((1ull << (tid - 64)) - 1ull))] = tid;
  if (tid == 0) base_s = cnt ? atomicAdd(slotctr, (unsigned int)cnt) : 0u;
  __syncthreads();
  unsigned int base = base_s;

  int r = tid >> 3, ch = tid & 7;
  int idx0 = r, idx1 = r + 32;
  if (idx1 < cnt) {                                 // pair path, loads in-loop
    int row0 = rbase + pos[idx0], row1 = rbase + pos[idx1];
    const float* xr0 = x + (size_t)row0 * D + ch * 4;
    const float* xr1 = x + (size_t)row1 * D + ch * 4;
    float pd0[16], pd1[16];
#pragma unroll
    for (int c = 0; c < 16; ++c) { pd0[c] = 0.f; pd1[c] = 0.f; }
#pragma unroll 2
    for (int j = 0; j < 10; ++j) {                  // 2 loads/iter -> no spill
      float4 xv0 = *(const float4*)(xr0 + j * 32);
      float4 xv1 = *(const float4*)(xr1 + j * 32);
#pragma unroll
      for (int c = 0; c < 16; ++c) {                // shared W read, 2 rows
        const float4 wv = *(const float4*)&Wl[c * D + j * 32 + ch * 4];
        float a0 = fmaf(xv0.x, wv.x, pd0[c]);
        a0 = fmaf(xv0.y, wv.y, a0);
        a0 = fmaf(xv0.z, wv.z, a0);
        pd0[c] = fmaf(xv0.w, wv.w, a0);
        float a1 = fmaf(xv1.x, wv.x, pd1[c]);
        a1 = fmaf(xv1.y, wv.y, a1);
        a1 = fmaf(xv1.z, wv.z, a1);
        pd1[c] = fmaf(xv1.w, wv.w, a1);
      }
    }
#pragma unroll
    for (int c = 0; c < 16; ++c) {
      pd0[c] += __shfl_xor(pd0[c], 1);
      pd0[c] += __shfl_xor(pd0[c], 2);
      pd0[c] += __shfl_xor(pd0[c], 4);
    }
#pragma unroll
    for (int c = 0; c < 16; ++c) {
      pd1[c] += __shfl_xor(pd1[c], 1);
      pd1[c] += __shfl_xor(pd1[c], 2);
      pd1[c] += __shfl_xor(pd1[c], 4);
    }
    if (ch == 0) {
      store_t(pd0, (int)base + idx0, row0, t2arr, origrow, tbf32);
      store_t(pd1, (int)base + idx1, row1, t2arr, origrow, tbf32);
    }
  } else if (idx0 < cnt) {                          // single tail
    int row = rbase + pos[idx0];
    float pd[16];
    proj_lds(x, Wl, row, ch, pd);
    if (ch == 0) store_t(pd, (int)base + idx0, row, t2arr, origrow, tbf32);
  }
  for (int idx = r + 64; idx < cnt; idx += 32) {    // overflow ranks (rare)
    int row = rbase + pos[idx];
    float pd[16];
    proj_lds(x, Wl, row, ch, pd);
    if (ch == 0) store_t(pd, (int)base + idx, row, t2arr, origrow, tbf32);
  }
}

// ---------------- Kernel 2: MFMA fold screening (2048 x 256, R14-verbatim) ---
__global__ __launch_bounds__(256) void phase1_kernel(
    const unsigned short* __restrict__ tbf32,
    const unsigned short* __restrict__ cbf32,
    unsigned int* __restrict__ rowmin_u) {
  __shared__ unsigned int rml[4 * 33];
  int tid = threadIdx.x;
  int w = tid >> 6, l = tid & 63, lr = l & 15, g = l >> 4;
  int strip = (int)blockIdx.x >> 2;                 // 0..511
  int seg   = ((int)blockIdx.x & 3) * 4 + w;        // 0..15
  int row0 = strip * 32;

  for (int i = tid; i < 4 * 33; i += 256) rml[i] = 0xFFFFFFFFu;
  __syncthreads();

  const f32x4 zero = {0.f, 0.f, 0.f, 0.f};
  short8 calA = {0,0,0,0,0,0,0,0}, calB = {0,0,0,0,0,0,0,0};
  if (g == 0) {
    calA[0] = (short)f2bf((float)(lr + 1));
    calB[0] = (short)0x3F80;                        // bf16 1.0
  }
  f32x4 cal = __builtin_amdgcn_mfma_f32_16x16x32_bf16(calA, calB, zero, 0, 0, 0);
  int rid[4];
#pragma unroll
  for (int j = 0; j < 4; ++j) {
    int v = (int)(cal[j] + 0.5f) - 1;
    rid[j] = v < 0 ? 0 : (v > 15 ? 15 : v);
  }

  const short8 a0 = *(const short8*)(tbf32 + (long)(row0 + lr) * 32 + g * 8);
  const short8 a1 = *(const short8*)(tbf32 + (long)(row0 + 16 + lr) * 32 + g * 8);
  f32x4 rmin0 = {3.4e38f, 3.4e38f, 3.4e38f, 3.4e38f};
  f32x4 rmin1 = rmin0;
  int code0 = seg * 512;
#pragma unroll 2
  for (int t = 0; t < 32; ++t) {
    int code = code0 + t * 16 + lr;
    short8 b = *(const short8*)(cbf32 + (long)code * 32 + g * 8);
    f32x4 d0 = __builtin_amdgcn_mfma_f32_16x16x32_bf16(a0, b, zero, 0, 0, 0);
    f32x4 d1 = __builtin_amdgcn_mfma_f32_16x16x32_bf16(a1, b, zero, 0, 0, 0);
#pragma unroll
    for (int j = 0; j < 4; ++j) {
      rmin0[j] = fminf(rmin0[j], d0[j]);
      rmin1[j] = fminf(rmin1[j], d1[j]);
    }
  }
  unsigned int* mywave = &rml[w * 33];
#pragma unroll
  for (int j = 0; j < 4; ++j) {
    atomicMin(&mywave[rid[j]],      encf(rmin0[j]));
    atomicMin(&mywave[16 + rid[j]], encf(rmin1[j]));
  }
  __syncthreads();
  if (tid < 32) {
    unsigned int mn = 0xFFFFFFFFu;
#pragma unroll
    for (int ww = 0; ww < 4; ++ww) mn = min(mn, rml[ww * 33 + tid]);
    atomicMin(&rowmin_u[row0 + tid], mn);
  }
}

// ---------------- Kernel 3: gate (1 block x 1024, R14-verbatim) --------------
__global__ __launch_bounds__(1024) void gate_kernel(
    const unsigned int* __restrict__ rowmin_u, const float* __restrict__ t2arr,
    const float* __restrict__ c2,
    unsigned int* __restrict__ candcount, int* __restrict__ candlist) {
  __shared__ float red_f[1024];
  __shared__ float c2m_s;
  __shared__ unsigned int cnt;
  int tid = threadIdx.x;
  float cm = 0.f;                                   // c2 >= 0
#pragma unroll
  for (int i = 0; i < 8; ++i) cm = fmaxf(cm, c2[tid + i * 1024]);
  red_f[tid] = cm;
  if (tid == 0) cnt = 0u;
  __syncthreads();
  for (int st = 512; st > 0; st >>= 1) {
    if (tid < st) red_f[tid] = fmaxf(red_f[tid], red_f[tid + st]);
    __syncthreads();
  }
  if (tid == 0) c2m_s = red_f[0];
  __syncthreads();
  float c2m = c2m_s;
  float Tl = 3.4e38f;
  for (int i = tid; i < NMASK; i += 1024) {
    float a = decf(rowmin_u[i]);
    float e = fmaf(EPS_C, sqrtf(t2arr[i] * c2m), EPS_ABS);
    Tl = fminf(Tl, a + e);                          // NaN -> ignored
  }
  red_f[tid] = Tl;
  __syncthreads();
  for (int st = 512; st > 0; st >>= 1) {
    if (tid < st) red_f[tid] = fminf(red_f[tid], red_f[tid + st]);
    __syncthreads();
  }
  float T = red_f[0];
  for (int i = tid; i < NMASK; i += 1024) {
    float a = decf(rowmin_u[i]);
    float e = fmaf(EPS_C, sqrtf(t2arr[i] * c2m), EPS_ABS);
    if (!(a - e > T)) {                             // NaN-safe: NaN -> candidate
      unsigned int pos = atomicAdd(&cnt, 1u);
      candlist[pos] = i;
    }
  }
  __syncthreads();
  if (tid == 0) candcount[0] = cnt;                 // plain store
}

// ---------------- Kernel 4: cproj (512 x 256, R14-verbatim) ------------------
__global__ __launch_bounds__(256) void cproj_kernel(
    const float* __restrict__ x, const float* __restrict__ W,
    const int* __restrict__ origrow, const unsigned int* __restrict__ candcount,
    const int* __restrict__ candlist, float* __restrict__ tgtm) {
  int tid = threadIdx.x, bid = (int)blockIdx.x;
  int nc = (int)candcount[0];
  if (bid * 32 >= nc) return;                       // whole block idle
  __shared__ float Wl[CDIM * D];                    // 20 KiB
  for (int i = tid; i < (CDIM * D) / 4; i += 256)
    ((float4*)Wl)[i] = ((const float4*)W)[i];
  __syncthreads();
  int idx = bid * 32 + (tid >> 3);                  // candidate index
  int ch  = tid & 7;
  if (idx >= nc) return;
  int row = origrow[candlist[idx]];
  float pd[16];
  proj_lds(x, Wl, row, ch, pd);                     // bit-identical chain
  if (ch == 0) {
    float* op = tgtm + (long)idx * 16;
#pragma unroll
    for (int c = 0; c < 16; ++c) op[c] = -2.0f * pd[c];
  }
}

// ---------------- Kernel 5: rescore + rank emit (512 x 256, R14-verbatim) ----
__global__ __launch_bounds__(256) void rescore_kernel(
    const float* __restrict__ cbk, const float* __restrict__ c2,
    const float* __restrict__ tgtm, const float* __restrict__ t2arr,
    const int* __restrict__ origrow, const int* __restrict__ mask,
    const unsigned int* __restrict__ candcount, const int* __restrict__ candlist,
    unsigned long long* __restrict__ key, unsigned int* __restrict__ resctr,
    int* __restrict__ out) {
  __shared__ unsigned long long red[256];
  __shared__ int lastf;
  __shared__ unsigned int vlow_s;
  int tid = threadIdx.x, bid = (int)blockIdx.x;
  int nwork = (int)candcount[0] * 8;                // 8 octants x 1024 codes
  for (int wk = bid; wk < nwork; wk += (int)gridDim.x) {
    int ci = wk >> 3, oct = wk & 7;
    int r = candlist[ci];                           // slot, uniform per block
    float t2 = t2arr[r];
    int row = origrow[r];
    float tm[16];
    const float4* tp = (const float4*)(tgtm + (long)ci * 16);
#pragma unroll
    for (int q = 0; q < 4; ++q) {                   // uniform -> scalar loads
      float4 v = tp[q];
      tm[q*4+0] = v.x; tm[q*4+1] = v.y; tm[q*4+2] = v.z; tm[q*4+3] = v.w;
    }
    float minv = 3.4e38f; int mink = 0;
#pragma unroll 2
    for (int k = 0; k < 4; ++k) {                   // 4 codes/thread
      int code = oct * 1024 + k * 256 + tid;
      const float4* cp = (const float4*)(cbk + (long)code * CDIM);
      float4 c0 = cp[0], c1 = cp[1], c2v4 = cp[2], c3 = cp[3];
      float acc = fmaf(tm[0],  c0.x, c2[code]);
      acc = fmaf(tm[1],  c0.y, acc);   acc = fmaf(tm[2],  c0.z, acc);
      acc = fmaf(tm[3],  c0.w, acc);   acc = fmaf(tm[4],  c1.x, acc);
      acc = fmaf(tm[5],  c1.y, acc);   acc = fmaf(tm[6],  c1.z, acc);
      acc = fmaf(tm[7],  c1.w, acc);   acc = fmaf(tm[8],  c2v4.x, acc);
      acc = fmaf(tm[9],  c2v4.y, acc); acc = fmaf(tm[10], c2v4.z, acc);
      acc = fmaf(tm[11], c2v4.w, acc); acc = fmaf(tm[12], c3.x, acc);
      acc = fmaf(tm[13], c3.y, acc);   acc = fmaf(tm[14], c3.z, acc);
      acc = fmaf(tm[15], c3.w, acc);
      if (acc < minv) { minv = acc; mink = code; }
    }
    // tie-break on row*8192+code == lexicographic (row, code) == rank order
    red[tid] = ((unsigned long long)encf(t2 + minv) << 32)
        | (unsigned long long)((unsigned int)row * (unsigned int)NCODES + (unsigned int)mink);
    __syncthreads();
    for (int s = 128; s > 0; s >>= 1) {
      if (tid < s) { if (red[tid + s] < red[tid]) red[tid] = red[tid + s]; }
      __syncthreads();
    }
    if (tid == 0) atomicMin(key, red[0]);
    __syncthreads();                                // LDS reuse across wk
  }
  if (tid == 0) {
    __threadfence();
    lastf = (atomicAdd(resctr, 1u) == (unsigned int)gridDim.x - 1u) ? 1 : 0;
  }
  __syncthreads();
  if (lastf) {                                      // last block: rank + emit
    if (tid == 0)
      vlow_s = (unsigned int)(atomicMin(key, 0xFFFFFFFFFFFFFFFFull) & 0xFFFFFFFFull);
    __syncthreads();
    unsigned int vlow = vlow_s;
    int wrow = (int)(vlow >> 13), wcode = (int)(vlow & 8191u);
    int lo = tid * (NROWS / 256);
    int hi = lo + (NROWS / 256); if (hi > wrow) hi = wrow;
    int cnt = 0;
#pragma unroll 4
    for (int i = lo; i < hi; ++i) cnt += (mask[i] != 0);
    __shared__ int ps[256];
    ps[tid] = cnt;
    __syncthreads();
    for (int s = 128; s > 0; s >>= 1) {
      if (tid < s) ps[tid] += ps[tid + s];
      __syncthreads();
    }
    if (tid == 0) out[0] = ps[0] * NCODES + wcode;  // rank*8192 + code
  }
}

extern "C" void kernel_launch(void* const* d_in, const int* in_sizes, int n_in,
                              void* d_out, int out_size, void* d_ws, size_t ws_size,
                              hipStream_t stream) {
  const float* x    = (const float*)d_in[0];
  const int*   mask = (const int*)d_in[1];
  const float* W    = (const float*)d_in[2];
  const float* cbk  = (const float*)d_in[3];
  int* out = (int*)d_out;

  char* ws = (char*)d_ws;                                   // total 1,810,432 B (R14-proven)
  unsigned int*       ctrs      = (unsigned int*)(ws + 4096);
  unsigned int*       slotctr   = (unsigned int*)(ws + 4096);
  unsigned int*       resctr    = (unsigned int*)(ws + 4100);
  unsigned int*       candcount = (unsigned int*)(ws + 4112);       // gate stores
  unsigned long long* key       = (unsigned long long*)(ws + 8184); // init
  unsigned int*       rowmin_u  = (unsigned int*)(ws + 8192);       // 64 KiB (project inits)
  float*              t2arr     = (float*)(ws + 73728);             // 64 KiB
  int*                origrow   = (int*)(ws + 139264);              // 64 KiB
  float*              c2        = (float*)(ws + 204800);            // 32 KiB
  unsigned short*     cbf32     = (unsigned short*)(ws + 237568);   // 512 KiB
  int*                candlist  = (int*)(ws + 237568);              // aliases cbf32 (dead by gate)
  unsigned short*     tbf32     = (unsigned short*)(ws + 761856);   // 1 MiB
  float*              tgtm      = (float*)(ws + 761856);            // aliases tbf32 (dead after phase1)

  init_kernel<<<1, 64, 0, stream>>>(ctrs, key);
  project_kernel<<<256, 256, 0, stream>>>(x, mask, W, cbk, c2, cbf32, tbf32,
                                          t2arr, origrow, rowmin_u, slotctr);
  phase1_kernel<<<2048, 256, 0, stream>>>(tbf32, cbf32, rowmin_u);
  gate_kernel<<<1, 1024, 0, stream>>>(rowmin_u, t2arr, c2, candcount, candlist);
  cproj_kernel<<<512, 256, 0, stream>>>(x, W, origrow, candcount, candlist, tgtm);
  rescore_kernel<<<512, 256, 0, stream>>>(cbk, c2, tgtm, t2arr, origrow, mask,
                                          candcount, candlist, key, resctr, out);
}